// Round 15
// baseline (143.184 us; speedup 1.0000x reference)
//
#include <hip/hip_runtime.h>
#include <hip/hip_fp16.h>

#define CNUM 29
#define HH 256
#define WW 256
#define BB 2
#define KK 7
#define HALO 3
#define TX 32
#define TY 4
#define LW (TX + 2*HALO)   // 38
#define LH (TY + 2*HALO)   // 10
#define NPIX (LH*LW)       // 380
#define HWP (HH*WW)        // 65536

// 1-D normalized Gaussian, sigma=3.0, K=7 (exp(-d^2/18)/sum)
__device__ constexpr float GW[KK] = {
    0.106287146f, 0.140321912f, 0.165770643f, 0.175240699f,
    0.165770643f, 0.140321912f, 0.106287146f};

__device__ __forceinline__ unsigned packh2(float a, float b) {
    __half2 h = __floats2half2_rn(a, b);
    return *reinterpret_cast<unsigned*>(&h);
}
__device__ __forceinline__ float2 unpkh2(unsigned u) {
    __half2 h = *reinterpret_cast<__half2*>(&u);
    return __half22float2(h);
}

// One CRF iteration. 256 threads per 32x4 tile, tap-split (A: rows 4-6 = 21
// taps, B: rows 0-3 = 28 taps), split epilogue (A: ch 0-15, B: ch 16-28),
// no-max softmax with 1-scalar sum exchange. r15 change: the per-half packed
// -unary (uh) load is issued right after the tap loop, so its L2 latency is
// covered by the cross-write + 2 join barriers instead of sitting on the
// epilogue critical path (+8 VGPR over a short range only). img LDS as
// float2+float planes. Global q fp16 channel-last [pix][4 x uint4]; blocks
// XCD-chunk swizzled (bijective, 1024 % 8 == 0).
template <bool FIRST, bool LAST>
__global__ __launch_bounds__(256) void crf_iter(const float* __restrict__ unary,
                                                const float* __restrict__ img,
                                                const uint4* __restrict__ qin,
                                                uint4* __restrict__ qout,
                                                uint4* __restrict__ uh,
                                                float* __restrict__ outf) {
    __shared__ uint4  s_q4[NPIX * 4];     // 24,320 B; aliased: partial[29][128], relay
    __shared__ float2 s_im2[NPIX];        //  3,040 B (img ch0,ch1)
    __shared__ float  s_imz[NPIX];        //  1,520 B (img ch2)
    __shared__ float  s_red[2][128];      //  1,024 B (sum exchange)

    const int tid = threadIdx.x;
    const bool isA = tid < 128;           // wave-uniform half
    const int lid = tid & 127;
    const int tx = lid & (TX - 1);
    const int ty = lid >> 5;              // 0..3

    // XCD-chunked bijective swizzle (1024 % 8 == 0)
    const int flat = (blockIdx.z << 9) | (blockIdx.y << 3) | blockIdx.x;  // 0..1023
    const int sid  = ((flat & 7) << 7) | (flat >> 3);
    const int b    = sid >> 9;
    const int rem  = sid & 511;
    const int by   = (rem >> 3) * TY;
    const int bx   = (rem & 7) * TX;
    const int pix  = (by + ty) * WW + (bx + tx);

    const float* ubase = unary + (size_t)b * CNUM * HWP;
    const float* imgb  = img + (size_t)b * 3 * HWP;

    // ---- stage: img (float2+float planes) + q (fp16 chunks, XOR-swizzled) ----
    if (FIRST) {
        for (int t = tid; t < NPIX; t += 256) {
            int r = t / LW, cc = t - r * LW;
            int gy = by + r - HALO, gx = bx + cc - HALO;
            bool ok = (gy >= 0) & (gy < HH) & (gx >= 0) & (gx < WW);
            int goff = ok ? gy * WW + gx : 0;
            float i0 = imgb[goff], i1 = imgb[HWP + goff], i2 = imgb[2 * HWP + goff];
            if (!ok) { i0 = 0.f; i1 = 0.f; i2 = 0.f; }
            float2 v2; v2.x = i0; v2.y = i1;
            s_im2[t] = v2; s_imz[t] = i2;

            float nu[CNUM];
#pragma unroll
            for (int c = 0; c < CNUM; ++c) nu[c] = -ubase[(size_t)c * HWP + goff];
            bool interior = (r >= HALO) & (r < LH - HALO) & (cc >= HALO) & (cc < LW - HALO);
            if (interior) {  // pre-pack -unary fp16 (each pixel owned by one block)
                uint4* up = uh + ((size_t)b * HWP + goff) * 4;
                uint4 u0, u1, u2, u3;
                u0.x = packh2(nu[0],  nu[1]);  u0.y = packh2(nu[2],  nu[3]);
                u0.z = packh2(nu[4],  nu[5]);  u0.w = packh2(nu[6],  nu[7]);
                u1.x = packh2(nu[8],  nu[9]);  u1.y = packh2(nu[10], nu[11]);
                u1.z = packh2(nu[12], nu[13]); u1.w = packh2(nu[14], nu[15]);
                u2.x = packh2(nu[16], nu[17]); u2.y = packh2(nu[18], nu[19]);
                u2.z = packh2(nu[20], nu[21]); u2.w = packh2(nu[22], nu[23]);
                u3.x = packh2(nu[24], nu[25]); u3.y = packh2(nu[26], nu[27]);
                u3.z = packh2(nu[28], 0.f);    u3.w = 0u;
                up[0] = u0; up[1] = u1; up[2] = u2; up[3] = u3;
            }
            // no-max softmax: -unary bounded -> exp f32-safe
            float ss = 0.f;
            float v[CNUM];
#pragma unroll
            for (int c = 0; c < CNUM; ++c) { v[c] = __expf(nu[c]); ss += v[c]; }
            float inv = ok ? 1.f / ss : 0.f;
#pragma unroll
            for (int c = 0; c < CNUM; ++c) v[c] *= inv;
            const int swz = (t >> 1) & 3;
            uint4 p0, p1, p2, p3;
            p0.x = packh2(v[0],  v[1]);  p0.y = packh2(v[2],  v[3]);
            p0.z = packh2(v[4],  v[5]);  p0.w = packh2(v[6],  v[7]);
            p1.x = packh2(v[8],  v[9]);  p1.y = packh2(v[10], v[11]);
            p1.z = packh2(v[12], v[13]); p1.w = packh2(v[14], v[15]);
            p2.x = packh2(v[16], v[17]); p2.y = packh2(v[18], v[19]);
            p2.z = packh2(v[20], v[21]); p2.w = packh2(v[22], v[23]);
            p3.x = packh2(v[24], v[25]); p3.y = packh2(v[26], v[27]);
            p3.z = packh2(v[28], 0.f);   p3.w = 0u;
            s_q4[t * 4 + (0 ^ swz)] = p0;
            s_q4[t * 4 + (1 ^ swz)] = p1;
            s_q4[t * 4 + (2 ^ swz)] = p2;
            s_q4[t * 4 + (3 ^ swz)] = p3;
        }
    } else {
        // two staging rounds; all global loads issued before LDS writes
        int t = tid;
        int r = t / LW, cc = t - r * LW;
        int gy = by + r - HALO, gx = bx + cc - HALO;
        bool ok = (gy >= 0) & (gy < HH) & (gx >= 0) & (gx < WW);
        int goff = ok ? gy * WW + gx : 0;
        float i0 = imgb[goff], i1 = imgb[HWP + goff], i2 = imgb[2 * HWP + goff];
        const uint4* qp = qin + ((size_t)b * HWP + goff) * 4;
        uint4 p0 = qp[0], p1 = qp[1], p2 = qp[2], p3 = qp[3];

        int t2 = tid + 256;
        bool has2 = t2 < NPIX;
        int r2 = t2 / LW, cc2 = t2 - r2 * LW;
        int gy2 = by + r2 - HALO, gx2 = bx + cc2 - HALO;
        bool ok2 = has2 & (gy2 >= 0) & (gy2 < HH) & (gx2 >= 0) & (gx2 < WW);
        int goff2 = ok2 ? gy2 * WW + gx2 : 0;
        float j0 = 0.f, j1 = 0.f, j2 = 0.f;
        uint4 s0, s1, s2, s3;
        if (has2) {
            j0 = imgb[goff2]; j1 = imgb[HWP + goff2]; j2 = imgb[2 * HWP + goff2];
            const uint4* qp2 = qin + ((size_t)b * HWP + goff2) * 4;
            s0 = qp2[0]; s1 = qp2[1]; s2 = qp2[2]; s3 = qp2[3];
        }
        if (!ok) {
            i0 = 0.f; i1 = 0.f; i2 = 0.f;
            p0.x = p0.y = p0.z = p0.w = 0u; p1.x = p1.y = p1.z = p1.w = 0u;
            p2.x = p2.y = p2.z = p2.w = 0u; p3.x = p3.y = p3.z = p3.w = 0u;
        }
        float2 v2; v2.x = i0; v2.y = i1;
        s_im2[t] = v2; s_imz[t] = i2;
        const int swz = (t >> 1) & 3;
        s_q4[t * 4 + (0 ^ swz)] = p0;
        s_q4[t * 4 + (1 ^ swz)] = p1;
        s_q4[t * 4 + (2 ^ swz)] = p2;
        s_q4[t * 4 + (3 ^ swz)] = p3;
        if (has2) {
            if (!ok2) {
                j0 = 0.f; j1 = 0.f; j2 = 0.f;
                s0.x = s0.y = s0.z = s0.w = 0u; s1.x = s1.y = s1.z = s1.w = 0u;
                s2.x = s2.y = s2.z = s2.w = 0u; s3.x = s3.y = s3.z = s3.w = 0u;
            }
            float2 w2; w2.x = j0; w2.y = j1;
            s_im2[t2] = w2; s_imz[t2] = j2;
            const int swz2 = (t2 >> 1) & 3;
            s_q4[t2 * 4 + (0 ^ swz2)] = s0;
            s_q4[t2 * 4 + (1 ^ swz2)] = s1;
            s_q4[t2 * 4 + (2 ^ swz2)] = s2;
            s_q4[t2 * 4 + (3 ^ swz2)] = s3;
        }
    }
    __syncthreads();

    // ---- tap phase (kernel rows split between halves) ----
    const int tc = (ty + HALO) * LW + (tx + HALO);
    const float2 cv = s_im2[tc];
    const float c0 = cv.x;
    const float c1 = cv.y;
    const float c2 = s_imz[tc];

    float acc[CNUM];
#pragma unroll
    for (int c = 0; c < CNUM; ++c) acc[c] = 0.f;

#define TAP_BODY(ii)                                                        \
    {                                                                       \
        const int t = (ty + (ii)) * LW + (tx + j);                          \
        float2 iv = s_im2[t];                                               \
        float d0 = iv.x - c0;                                               \
        float d1 = iv.y - c1;                                               \
        float d2 = s_imz[t] - c2;                                           \
        float dsq = d0 * d0 + d1 * d1 + d2 * d2;                            \
        float w = (GW[(ii)] * GW[j]) * (3.0f + 10.0f * __expf(dsq * -0.005f)); \
        const int t4 = t * 4;                                               \
        const int swz = (t >> 1) & 3;                                       \
        uint4 q0 = s_q4[t4 + (0 ^ swz)];                                    \
        uint4 q1 = s_q4[t4 + (1 ^ swz)];                                    \
        uint4 q2 = s_q4[t4 + (2 ^ swz)];                                    \
        uint4 q3 = s_q4[t4 + (3 ^ swz)];                                    \
        const unsigned* u0 = &q0.x;                                         \
        const unsigned* u1 = &q1.x;                                         \
        const unsigned* u2 = &q2.x;                                         \
        _Pragma("unroll")                                                   \
        for (int k = 0; k < 4; ++k) {                                       \
            float2 f = unpkh2(u0[k]);                                       \
            acc[2 * k]     += w * f.x;                                      \
            acc[2 * k + 1] += w * f.y;                                      \
        }                                                                   \
        _Pragma("unroll")                                                   \
        for (int k = 0; k < 4; ++k) {                                       \
            float2 f = unpkh2(u1[k]);                                       \
            acc[8 + 2 * k]     += w * f.x;                                  \
            acc[8 + 2 * k + 1] += w * f.y;                                  \
        }                                                                   \
        _Pragma("unroll")                                                   \
        for (int k = 0; k < 4; ++k) {                                       \
            float2 f = unpkh2(u2[k]);                                       \
            acc[16 + 2 * k]     += w * f.x;                                 \
            acc[16 + 2 * k + 1] += w * f.y;                                 \
        }                                                                   \
        {                                                                   \
            float2 f = unpkh2(q3.x);                                        \
            acc[24] += w * f.x; acc[25] += w * f.y;                         \
            f = unpkh2(q3.y);                                               \
            acc[26] += w * f.x; acc[27] += w * f.y;                         \
            f = unpkh2(q3.z);                                               \
            acc[28] += w * f.x;                                             \
        }                                                                   \
    }

    __builtin_amdgcn_s_setprio(1);
    if (isA) {   // rows 4-6 (21 taps)
#pragma unroll
        for (int i = 4; i < KK; ++i)
#pragma unroll
            for (int j = 0; j < KK; ++j) TAP_BODY(i)
    } else {     // rows 0-3 (28 taps)
#pragma unroll
        for (int i = 0; i < 4; ++i)
#pragma unroll
            for (int j = 0; j < KK; ++j) TAP_BODY(i)
    }
    __builtin_amdgcn_s_setprio(0);
#undef TAP_BODY

    // ---- hoisted epilogue -unary load: issue now, consume after 2 barriers ----
    uint4 nh0, nh1;
    if (!FIRST) {
        const uint4* up = uh + ((size_t)b * HWP + pix) * 4;
        if (isA) { nh0 = up[0]; nh1 = up[1]; }
        else     { nh0 = up[2]; nh1 = up[3]; }
    }

    // ---- cross-write partials: B -> ch 0-15 (A's), A -> ch 16-28 (B's) ----
    __syncthreads();                       // all s_q4 tap reads complete
    float* s_part = reinterpret_cast<float*>(s_q4);   // 29*128*4 = 14,848 B
    if (isA) {
#pragma unroll
        for (int c = 16; c < CNUM; ++c) s_part[c * 128 + lid] = acc[c];
    } else {
#pragma unroll
        for (int c = 0; c < 16; ++c) s_part[c * 128 + lid] = acc[c];
    }
    __syncthreads();

    // ---- split epilogue: A owns ch 0-15, B owns ch 16-28; no-max softmax ----
    float l[16];
    float ss_loc = 0.f;
    if (isA) {
        float nu[16];
        if (FIRST) {
#pragma unroll
            for (int c = 0; c < 16; ++c) nu[c] = -ubase[(size_t)c * HWP + pix];
        } else {
            const unsigned* w0 = &nh0.x;
            const unsigned* w1 = &nh1.x;
#pragma unroll
            for (int k = 0; k < 4; ++k) {
                float2 f = unpkh2(w0[k]); nu[2 * k] = f.x; nu[2 * k + 1] = f.y;
            }
#pragma unroll
            for (int k = 0; k < 4; ++k) {
                float2 f = unpkh2(w1[k]); nu[8 + 2 * k] = f.x; nu[8 + 2 * k + 1] = f.y;
            }
        }
#pragma unroll
        for (int c = 0; c < 16; ++c) {
            l[c] = __expf(acc[c] + s_part[c * 128 + lid] + nu[c]);
            ss_loc += l[c];
        }
    } else {
        float nu[13];
        if (FIRST) {
#pragma unroll
            for (int c = 0; c < 13; ++c) nu[c] = -ubase[(size_t)(16 + c) * HWP + pix];
        } else {
            const unsigned* w2 = &nh0.x;
#pragma unroll
            for (int k = 0; k < 4; ++k) {
                float2 f = unpkh2(w2[k]); nu[2 * k] = f.x; nu[2 * k + 1] = f.y;
            }
            { float2 f = unpkh2(nh1.x); nu[8]  = f.x; nu[9]  = f.y; }
            { float2 f = unpkh2(nh1.y); nu[10] = f.x; nu[11] = f.y; }
            { float2 f = unpkh2(nh1.z); nu[12] = f.x; }
        }
#pragma unroll
        for (int c = 0; c < 13; ++c) {
            l[c] = __expf(acc[16 + c] + s_part[(16 + c) * 128 + lid] + nu[c]);
            ss_loc += l[c];
        }
    }
    s_red[isA ? 0 : 1][lid] = ss_loc;
    __syncthreads();
    const float inv = 1.0f / (s_red[0][lid] + s_red[1][lid]);

    if (LAST) {
        float* qo = outf + (size_t)b * CNUM * HWP + pix;
        if (isA) {
#pragma unroll
            for (int c = 0; c < 16; ++c) qo[(size_t)c * HWP] = l[c] * inv;
        } else {
#pragma unroll
            for (int c = 0; c < 13; ++c) qo[(size_t)(16 + c) * HWP] = l[c] * inv;
        }
    } else {
        uint4* s_xf = reinterpret_cast<uint4*>(s_q4);   // relay (region dead)
        if (!isA) {
            uint4 p2, p3;
            p2.x = packh2(l[0] * inv,  l[1] * inv);    // ch16,17
            p2.y = packh2(l[2] * inv,  l[3] * inv);
            p2.z = packh2(l[4] * inv,  l[5] * inv);
            p2.w = packh2(l[6] * inv,  l[7] * inv);
            p3.x = packh2(l[8] * inv,  l[9] * inv);
            p3.y = packh2(l[10] * inv, l[11] * inv);
            p3.z = packh2(l[12] * inv, 0.f);           // ch28
            p3.w = 0u;
            s_xf[lid * 2 + 0] = p2;
            s_xf[lid * 2 + 1] = p3;
        }
        __syncthreads();
        if (isA) {
            uint4 p0, p1;
            p0.x = packh2(l[0] * inv,  l[1] * inv);
            p0.y = packh2(l[2] * inv,  l[3] * inv);
            p0.z = packh2(l[4] * inv,  l[5] * inv);
            p0.w = packh2(l[6] * inv,  l[7] * inv);
            p1.x = packh2(l[8] * inv,  l[9] * inv);
            p1.y = packh2(l[10] * inv, l[11] * inv);
            p1.z = packh2(l[12] * inv, l[13] * inv);
            p1.w = packh2(l[14] * inv, l[15] * inv);
            uint4 p2 = s_xf[lid * 2 + 0];
            uint4 p3 = s_xf[lid * 2 + 1];
            uint4* qo = qout + ((size_t)b * HWP + pix) * 4;
            qo[0] = p0; qo[1] = p1; qo[2] = p2; qo[3] = p3;
        }
    }
}

extern "C" void kernel_launch(void* const* d_in, const int* in_sizes, int n_in,
                              void* d_out, int out_size, void* d_ws, size_t ws_size,
                              hipStream_t stream) {
    const float* unary = (const float*)d_in[0];
    const float* img   = (const float*)d_in[1];
    // ws: qA (8.39MB) | qB (8.39MB) | uh (8.39MB) = 25.2 MB
    const size_t QBYTES = (size_t)BB * HWP * 64;
    uint4* qA = (uint4*)d_ws;
    uint4* qB = (uint4*)((char*)d_ws + QBYTES);
    uint4* uh = (uint4*)((char*)d_ws + 2 * QBYTES);
    float* outf = (float*)d_out;

    dim3 grid(WW / TX, HH / TY, BB);   // (8, 64, 2) = 1024 blocks
    crf_iter<true,  false><<<grid, 256, 0, stream>>>(unary, img, qB, qA, uh, outf); // i1 -> qA
    crf_iter<false, false><<<grid, 256, 0, stream>>>(unary, img, qA, qB, uh, outf); // i2
    crf_iter<false, false><<<grid, 256, 0, stream>>>(unary, img, qB, qA, uh, outf); // i3
    crf_iter<false, false><<<grid, 256, 0, stream>>>(unary, img, qA, qB, uh, outf); // i4
    crf_iter<false, true ><<<grid, 256, 0, stream>>>(unary, img, qB, qA, uh, outf); // i5 -> d_out
}

// Round 16
// 90.117 us; speedup vs baseline: 1.5889x; 1.5889x over previous
//
#include <hip/hip_runtime.h>
#include <hip/hip_fp16.h>

#define CNUM 29
#define HH 256
#define WW 256
#define BB 2
#define KK 7
#define HALO 3
#define TX 32
#define TY 4
#define LW (TX + 2*HALO)   // 38
#define LH (TY + 2*HALO)   // 10
#define NPIX (LH*LW)       // 380
#define HWP (HH*WW)        // 65536

// 1-D normalized Gaussian, sigma=3.0, K=7 (exp(-d^2/18)/sum)
__device__ constexpr float GW[KK] = {
    0.106287146f, 0.140321912f, 0.165770643f, 0.175240699f,
    0.165770643f, 0.140321912f, 0.106287146f};

__device__ __forceinline__ unsigned packh2(float a, float b) {
    __half2 h = __floats2half2_rn(a, b);
    return *reinterpret_cast<unsigned*>(&h);
}
__device__ __forceinline__ float2 unpkh2(unsigned u) {
    __half2 h = *reinterpret_cast<__half2*>(&u);
    return __half22float2(h);
}

// One CRF iteration (round-14 configuration — session best, 90.2 us).
// 256 threads per 32x4 tile, tap-split (A: rows 4-6 = 21 taps, B: rows 0-3 =
// 28 taps). Split epilogue: A owns ch 0-15, B owns ch 16-28; partials
// cross-written in s_part; softmax is NO-MAX (logits bounded -> exp f32-safe)
// with a single sum exchange via s_red; B relays its packed chunks through
// LDS so the global store stays one-thread-per-64B-line. img LDS as
// float2+float planes. Global q fp16 channel-last [pix][4 x uint4]; uh =
// packed -unary fp16 from FIRST, loaded AFTER the join barriers (hoisting it
// regressed 59% — r15). Blocks XCD-chunk swizzled (bijective, 1024%8==0).
template <bool FIRST, bool LAST>
__global__ __launch_bounds__(256) void crf_iter(const float* __restrict__ unary,
                                                const float* __restrict__ img,
                                                const uint4* __restrict__ qin,
                                                uint4* __restrict__ qout,
                                                uint4* __restrict__ uh,
                                                float* __restrict__ outf) {
    __shared__ uint4  s_q4[NPIX * 4];     // 24,320 B; aliased: partial[29][128], relay
    __shared__ float2 s_im2[NPIX];        //  3,040 B (img ch0,ch1)
    __shared__ float  s_imz[NPIX];        //  1,520 B (img ch2)
    __shared__ float  s_red[2][128];      //  1,024 B (sum exchange)

    const int tid = threadIdx.x;
    const bool isA = tid < 128;           // wave-uniform half
    const int lid = tid & 127;
    const int tx = lid & (TX - 1);
    const int ty = lid >> 5;              // 0..3

    // XCD-chunked bijective swizzle (1024 % 8 == 0)
    const int flat = (blockIdx.z << 9) | (blockIdx.y << 3) | blockIdx.x;  // 0..1023
    const int sid  = ((flat & 7) << 7) | (flat >> 3);
    const int b    = sid >> 9;
    const int rem  = sid & 511;
    const int by   = (rem >> 3) * TY;
    const int bx   = (rem & 7) * TX;
    const int pix  = (by + ty) * WW + (bx + tx);

    const float* ubase = unary + (size_t)b * CNUM * HWP;
    const float* imgb  = img + (size_t)b * 3 * HWP;

    // ---- stage: img (float2+float planes) + q (fp16 chunks, XOR-swizzled) ----
    if (FIRST) {
        for (int t = tid; t < NPIX; t += 256) {
            int r = t / LW, cc = t - r * LW;
            int gy = by + r - HALO, gx = bx + cc - HALO;
            bool ok = (gy >= 0) & (gy < HH) & (gx >= 0) & (gx < WW);
            int goff = ok ? gy * WW + gx : 0;
            float i0 = imgb[goff], i1 = imgb[HWP + goff], i2 = imgb[2 * HWP + goff];
            if (!ok) { i0 = 0.f; i1 = 0.f; i2 = 0.f; }
            float2 v2; v2.x = i0; v2.y = i1;
            s_im2[t] = v2; s_imz[t] = i2;

            float nu[CNUM];
#pragma unroll
            for (int c = 0; c < CNUM; ++c) nu[c] = -ubase[(size_t)c * HWP + goff];
            bool interior = (r >= HALO) & (r < LH - HALO) & (cc >= HALO) & (cc < LW - HALO);
            if (interior) {  // pre-pack -unary fp16 (each pixel owned by one block)
                uint4* up = uh + ((size_t)b * HWP + goff) * 4;
                uint4 u0, u1, u2, u3;
                u0.x = packh2(nu[0],  nu[1]);  u0.y = packh2(nu[2],  nu[3]);
                u0.z = packh2(nu[4],  nu[5]);  u0.w = packh2(nu[6],  nu[7]);
                u1.x = packh2(nu[8],  nu[9]);  u1.y = packh2(nu[10], nu[11]);
                u1.z = packh2(nu[12], nu[13]); u1.w = packh2(nu[14], nu[15]);
                u2.x = packh2(nu[16], nu[17]); u2.y = packh2(nu[18], nu[19]);
                u2.z = packh2(nu[20], nu[21]); u2.w = packh2(nu[22], nu[23]);
                u3.x = packh2(nu[24], nu[25]); u3.y = packh2(nu[26], nu[27]);
                u3.z = packh2(nu[28], 0.f);    u3.w = 0u;
                up[0] = u0; up[1] = u1; up[2] = u2; up[3] = u3;
            }
            // no-max softmax: -unary <= ~5.5 -> exp <= ~250, f32-safe
            float ss = 0.f;
            float v[CNUM];
#pragma unroll
            for (int c = 0; c < CNUM; ++c) { v[c] = __expf(nu[c]); ss += v[c]; }
            float inv = ok ? 1.f / ss : 0.f;
#pragma unroll
            for (int c = 0; c < CNUM; ++c) v[c] *= inv;
            const int swz = (t >> 1) & 3;
            uint4 p0, p1, p2, p3;
            p0.x = packh2(v[0],  v[1]);  p0.y = packh2(v[2],  v[3]);
            p0.z = packh2(v[4],  v[5]);  p0.w = packh2(v[6],  v[7]);
            p1.x = packh2(v[8],  v[9]);  p1.y = packh2(v[10], v[11]);
            p1.z = packh2(v[12], v[13]); p1.w = packh2(v[14], v[15]);
            p2.x = packh2(v[16], v[17]); p2.y = packh2(v[18], v[19]);
            p2.z = packh2(v[20], v[21]); p2.w = packh2(v[22], v[23]);
            p3.x = packh2(v[24], v[25]); p3.y = packh2(v[26], v[27]);
            p3.z = packh2(v[28], 0.f);   p3.w = 0u;
            s_q4[t * 4 + (0 ^ swz)] = p0;
            s_q4[t * 4 + (1 ^ swz)] = p1;
            s_q4[t * 4 + (2 ^ swz)] = p2;
            s_q4[t * 4 + (3 ^ swz)] = p3;
        }
    } else {
        // two staging rounds; all global loads issued before LDS writes
        int t = tid;
        int r = t / LW, cc = t - r * LW;
        int gy = by + r - HALO, gx = bx + cc - HALO;
        bool ok = (gy >= 0) & (gy < HH) & (gx >= 0) & (gx < WW);
        int goff = ok ? gy * WW + gx : 0;
        float i0 = imgb[goff], i1 = imgb[HWP + goff], i2 = imgb[2 * HWP + goff];
        const uint4* qp = qin + ((size_t)b * HWP + goff) * 4;
        uint4 p0 = qp[0], p1 = qp[1], p2 = qp[2], p3 = qp[3];

        int t2 = tid + 256;
        bool has2 = t2 < NPIX;
        int r2 = t2 / LW, cc2 = t2 - r2 * LW;
        int gy2 = by + r2 - HALO, gx2 = bx + cc2 - HALO;
        bool ok2 = has2 & (gy2 >= 0) & (gy2 < HH) & (gx2 >= 0) & (gx2 < WW);
        int goff2 = ok2 ? gy2 * WW + gx2 : 0;
        float j0 = 0.f, j1 = 0.f, j2 = 0.f;
        uint4 s0, s1, s2, s3;
        if (has2) {
            j0 = imgb[goff2]; j1 = imgb[HWP + goff2]; j2 = imgb[2 * HWP + goff2];
            const uint4* qp2 = qin + ((size_t)b * HWP + goff2) * 4;
            s0 = qp2[0]; s1 = qp2[1]; s2 = qp2[2]; s3 = qp2[3];
        }
        if (!ok) {
            i0 = 0.f; i1 = 0.f; i2 = 0.f;
            p0.x = p0.y = p0.z = p0.w = 0u; p1.x = p1.y = p1.z = p1.w = 0u;
            p2.x = p2.y = p2.z = p2.w = 0u; p3.x = p3.y = p3.z = p3.w = 0u;
        }
        float2 v2; v2.x = i0; v2.y = i1;
        s_im2[t] = v2; s_imz[t] = i2;
        const int swz = (t >> 1) & 3;
        s_q4[t * 4 + (0 ^ swz)] = p0;
        s_q4[t * 4 + (1 ^ swz)] = p1;
        s_q4[t * 4 + (2 ^ swz)] = p2;
        s_q4[t * 4 + (3 ^ swz)] = p3;
        if (has2) {
            if (!ok2) {
                j0 = 0.f; j1 = 0.f; j2 = 0.f;
                s0.x = s0.y = s0.z = s0.w = 0u; s1.x = s1.y = s1.z = s1.w = 0u;
                s2.x = s2.y = s2.z = s2.w = 0u; s3.x = s3.y = s3.z = s3.w = 0u;
            }
            float2 w2; w2.x = j0; w2.y = j1;
            s_im2[t2] = w2; s_imz[t2] = j2;
            const int swz2 = (t2 >> 1) & 3;
            s_q4[t2 * 4 + (0 ^ swz2)] = s0;
            s_q4[t2 * 4 + (1 ^ swz2)] = s1;
            s_q4[t2 * 4 + (2 ^ swz2)] = s2;
            s_q4[t2 * 4 + (3 ^ swz2)] = s3;
        }
    }
    __syncthreads();

    // ---- tap phase (kernel rows split between halves) ----
    const int tc = (ty + HALO) * LW + (tx + HALO);
    const float2 cv = s_im2[tc];
    const float c0 = cv.x;
    const float c1 = cv.y;
    const float c2 = s_imz[tc];

    float acc[CNUM];
#pragma unroll
    for (int c = 0; c < CNUM; ++c) acc[c] = 0.f;

#define TAP_BODY(ii)                                                        \
    {                                                                       \
        const int t = (ty + (ii)) * LW + (tx + j);                          \
        float2 iv = s_im2[t];                                               \
        float d0 = iv.x - c0;                                               \
        float d1 = iv.y - c1;                                               \
        float d2 = s_imz[t] - c2;                                           \
        float dsq = d0 * d0 + d1 * d1 + d2 * d2;                            \
        float w = (GW[(ii)] * GW[j]) * (3.0f + 10.0f * __expf(dsq * -0.005f)); \
        const int t4 = t * 4;                                               \
        const int swz = (t >> 1) & 3;                                       \
        uint4 q0 = s_q4[t4 + (0 ^ swz)];                                    \
        uint4 q1 = s_q4[t4 + (1 ^ swz)];                                    \
        uint4 q2 = s_q4[t4 + (2 ^ swz)];                                    \
        uint4 q3 = s_q4[t4 + (3 ^ swz)];                                    \
        const unsigned* u0 = &q0.x;                                         \
        const unsigned* u1 = &q1.x;                                         \
        const unsigned* u2 = &q2.x;                                         \
        _Pragma("unroll")                                                   \
        for (int k = 0; k < 4; ++k) {                                       \
            float2 f = unpkh2(u0[k]);                                       \
            acc[2 * k]     += w * f.x;                                      \
            acc[2 * k + 1] += w * f.y;                                      \
        }                                                                   \
        _Pragma("unroll")                                                   \
        for (int k = 0; k < 4; ++k) {                                       \
            float2 f = unpkh2(u1[k]);                                       \
            acc[8 + 2 * k]     += w * f.x;                                  \
            acc[8 + 2 * k + 1] += w * f.y;                                  \
        }                                                                   \
        _Pragma("unroll")                                                   \
        for (int k = 0; k < 4; ++k) {                                       \
            float2 f = unpkh2(u2[k]);                                       \
            acc[16 + 2 * k]     += w * f.x;                                 \
            acc[16 + 2 * k + 1] += w * f.y;                                 \
        }                                                                   \
        {                                                                   \
            float2 f = unpkh2(q3.x);                                        \
            acc[24] += w * f.x; acc[25] += w * f.y;                         \
            f = unpkh2(q3.y);                                               \
            acc[26] += w * f.x; acc[27] += w * f.y;                         \
            f = unpkh2(q3.z);                                               \
            acc[28] += w * f.x;                                             \
        }                                                                   \
    }

    __builtin_amdgcn_s_setprio(1);
    if (isA) {   // rows 4-6 (21 taps)
#pragma unroll
        for (int i = 4; i < KK; ++i)
#pragma unroll
            for (int j = 0; j < KK; ++j) TAP_BODY(i)
    } else {     // rows 0-3 (28 taps)
#pragma unroll
        for (int i = 0; i < 4; ++i)
#pragma unroll
            for (int j = 0; j < KK; ++j) TAP_BODY(i)
    }
    __builtin_amdgcn_s_setprio(0);
#undef TAP_BODY

    // ---- cross-write partials: B -> ch 0-15 (A's), A -> ch 16-28 (B's) ----
    __syncthreads();                       // all s_q4 tap reads complete
    float* s_part = reinterpret_cast<float*>(s_q4);   // 29*128*4 = 14,848 B
    if (isA) {
#pragma unroll
        for (int c = 16; c < CNUM; ++c) s_part[c * 128 + lid] = acc[c];
    } else {
#pragma unroll
        for (int c = 0; c < 16; ++c) s_part[c * 128 + lid] = acc[c];
    }
    __syncthreads();

    // ---- split epilogue: A owns ch 0-15, B owns ch 16-28; no-max softmax ----
    float l[16];
    float ss_loc = 0.f;
    if (isA) {
        float nu[16];
        if (FIRST) {
#pragma unroll
            for (int c = 0; c < 16; ++c) nu[c] = -ubase[(size_t)c * HWP + pix];
        } else {
            const uint4* up = uh + ((size_t)b * HWP + pix) * 4;
            uint4 n0 = up[0], n1 = up[1];
            const unsigned* w0 = &n0.x;
            const unsigned* w1 = &n1.x;
#pragma unroll
            for (int k = 0; k < 4; ++k) {
                float2 f = unpkh2(w0[k]); nu[2 * k] = f.x; nu[2 * k + 1] = f.y;
            }
#pragma unroll
            for (int k = 0; k < 4; ++k) {
                float2 f = unpkh2(w1[k]); nu[8 + 2 * k] = f.x; nu[8 + 2 * k + 1] = f.y;
            }
        }
#pragma unroll
        for (int c = 0; c < 16; ++c) {
            l[c] = __expf(acc[c] + s_part[c * 128 + lid] + nu[c]);
            ss_loc += l[c];
        }
    } else {
        float nu[13];
        if (FIRST) {
#pragma unroll
            for (int c = 0; c < 13; ++c) nu[c] = -ubase[(size_t)(16 + c) * HWP + pix];
        } else {
            const uint4* up = uh + ((size_t)b * HWP + pix) * 4;
            uint4 n2 = up[2], n3 = up[3];
            const unsigned* w2 = &n2.x;
#pragma unroll
            for (int k = 0; k < 4; ++k) {
                float2 f = unpkh2(w2[k]); nu[2 * k] = f.x; nu[2 * k + 1] = f.y;
            }
            { float2 f = unpkh2(n3.x); nu[8]  = f.x; nu[9]  = f.y; }
            { float2 f = unpkh2(n3.y); nu[10] = f.x; nu[11] = f.y; }
            { float2 f = unpkh2(n3.z); nu[12] = f.x; }
        }
#pragma unroll
        for (int c = 0; c < 13; ++c) {
            l[c] = __expf(acc[16 + c] + s_part[(16 + c) * 128 + lid] + nu[c]);
            ss_loc += l[c];
        }
    }
    s_red[isA ? 0 : 1][lid] = ss_loc;
    __syncthreads();
    const float inv = 1.0f / (s_red[0][lid] + s_red[1][lid]);

    if (LAST) {
        float* qo = outf + (size_t)b * CNUM * HWP + pix;
        if (isA) {
#pragma unroll
            for (int c = 0; c < 16; ++c) qo[(size_t)c * HWP] = l[c] * inv;
        } else {
#pragma unroll
            for (int c = 0; c < 13; ++c) qo[(size_t)(16 + c) * HWP] = l[c] * inv;
        }
    } else {
        uint4* s_xf = reinterpret_cast<uint4*>(s_q4);   // relay (region dead)
        if (!isA) {
            uint4 p2, p3;
            p2.x = packh2(l[0] * inv,  l[1] * inv);    // ch16,17
            p2.y = packh2(l[2] * inv,  l[3] * inv);
            p2.z = packh2(l[4] * inv,  l[5] * inv);
            p2.w = packh2(l[6] * inv,  l[7] * inv);
            p3.x = packh2(l[8] * inv,  l[9] * inv);
            p3.y = packh2(l[10] * inv, l[11] * inv);
            p3.z = packh2(l[12] * inv, 0.f);           // ch28
            p3.w = 0u;
            s_xf[lid * 2 + 0] = p2;
            s_xf[lid * 2 + 1] = p3;
        }
        __syncthreads();
        if (isA) {
            uint4 p0, p1;
            p0.x = packh2(l[0] * inv,  l[1] * inv);
            p0.y = packh2(l[2] * inv,  l[3] * inv);
            p0.z = packh2(l[4] * inv,  l[5] * inv);
            p0.w = packh2(l[6] * inv,  l[7] * inv);
            p1.x = packh2(l[8] * inv,  l[9] * inv);
            p1.y = packh2(l[10] * inv, l[11] * inv);
            p1.z = packh2(l[12] * inv, l[13] * inv);
            p1.w = packh2(l[14] * inv, l[15] * inv);
            uint4 p2 = s_xf[lid * 2 + 0];
            uint4 p3 = s_xf[lid * 2 + 1];
            uint4* qo = qout + ((size_t)b * HWP + pix) * 4;
            qo[0] = p0; qo[1] = p1; qo[2] = p2; qo[3] = p3;
        }
    }
}

extern "C" void kernel_launch(void* const* d_in, const int* in_sizes, int n_in,
                              void* d_out, int out_size, void* d_ws, size_t ws_size,
                              hipStream_t stream) {
    const float* unary = (const float*)d_in[0];
    const float* img   = (const float*)d_in[1];
    // ws: qA (8.39MB) | qB (8.39MB) | uh (8.39MB) = 25.2 MB
    const size_t QBYTES = (size_t)BB * HWP * 64;
    uint4* qA = (uint4*)d_ws;
    uint4* qB = (uint4*)((char*)d_ws + QBYTES);
    uint4* uh = (uint4*)((char*)d_ws + 2 * QBYTES);
    float* outf = (float*)d_out;

    dim3 grid(WW / TX, HH / TY, BB);   // (8, 64, 2) = 1024 blocks
    crf_iter<true,  false><<<grid, 256, 0, stream>>>(unary, img, qB, qA, uh, outf); // i1 -> qA
    crf_iter<false, false><<<grid, 256, 0, stream>>>(unary, img, qA, qB, uh, outf); // i2
    crf_iter<false, false><<<grid, 256, 0, stream>>>(unary, img, qB, qA, uh, outf); // i3
    crf_iter<false, false><<<grid, 256, 0, stream>>>(unary, img, qA, qB, uh, outf); // i4
    crf_iter<false, true ><<<grid, 256, 0, stream>>>(unary, img, qB, qA, uh, outf); // i5 -> d_out
}